// Round 6
// baseline (330.298 us; speedup 1.0000x reference)
//
#include <hip/hip_runtime.h>
#include <cstdint>
#include <cstddef>

// GAT forward on MI355X — CSR-gather formulation (no f32 atomics).
// Round 6: (1) gather computes each softmax weight once per (edge,head) lane
// and redistributes via shfl (was 8x redundant VALU); 32-bit h offsets.
// (2) linear reads x via wave-uniform scalar loads (SMEM pipe), W from LDS
// amortized over 8 rows/thread -> LDS-issue bottleneck removed.

// ---------------- Kernel 1: linear + logits ----------------
__global__ __launch_bounds__(256) void gat_linear(
    const float* __restrict__ x, const float* __restrict__ W,
    const float* __restrict__ att_src, const float* __restrict__ att_dst,
    float* __restrict__ h, float* __restrict__ a_src, float* __restrict__ a_dst,
    int N)
{
    __shared__ float Wl[128 * 64];   // 32 KB
    const int tid  = threadIdx.x;
    const int lane = tid & 63;
    const int wi   = tid >> 6;

    for (int i = tid; i < 2048; i += 256)
        reinterpret_cast<float4*>(Wl)[i] = reinterpret_cast<const float4*>(W)[i];
    const float atts = att_src[lane];
    const float attd = att_dst[lane];
    __syncthreads();

    for (int nb = blockIdx.x * 32; nb < N; nb += gridDim.x * 32) {
        const int r0 = nb + wi * 8;          // wave-uniform row base
        if (r0 >= N) continue;
        const int nrows = (N - r0 < 8) ? (N - r0) : 8;
        // force SGPR base so x reads become scalar (s_load) on the SMEM pipe
        const float* xw = x + (size_t)(unsigned)__builtin_amdgcn_readfirstlane(r0) * 128;

        float acc[8] = {0.f, 0.f, 0.f, 0.f, 0.f, 0.f, 0.f, 0.f};
        if (nrows == 8) {
            #pragma unroll 4
            for (int k4 = 0; k4 < 32; ++k4) {
                const int kb = k4 * 4;
                const float wa = Wl[(kb + 0) * 64 + lane];
                const float wb = Wl[(kb + 1) * 64 + lane];
                const float wc = Wl[(kb + 2) * 64 + lane];
                const float wd = Wl[(kb + 3) * 64 + lane];
                #pragma unroll
                for (int j = 0; j < 8; ++j) {
                    const float4 xv = *reinterpret_cast<const float4*>(xw + j * 128 + kb);
                    acc[j] += xv.x * wa + xv.y * wb + xv.z * wc + xv.w * wd;
                }
            }
        } else {
            #pragma unroll 4
            for (int k4 = 0; k4 < 32; ++k4) {
                const int kb = k4 * 4;
                const float wa = Wl[(kb + 0) * 64 + lane];
                const float wb = Wl[(kb + 1) * 64 + lane];
                const float wc = Wl[(kb + 2) * 64 + lane];
                const float wd = Wl[(kb + 3) * 64 + lane];
                #pragma unroll
                for (int j = 0; j < 8; ++j) {
                    const int jr = (j < nrows) ? j : (nrows - 1);   // clamped, discarded later
                    const float4 xv = *reinterpret_cast<const float4*>(xw + jr * 128 + kb);
                    acc[j] += xv.x * wa + xv.y * wb + xv.z * wc + xv.w * wd;
                }
            }
        }

        #pragma unroll
        for (int j = 0; j < 8; ++j) {
            const int node = r0 + j;
            if (j < nrows) {
                h[(size_t)node * 64 + lane] = acc[j];
                float vs = acc[j] * atts;
                float vd = acc[j] * attd;
                vs += __shfl_xor(vs, 1, 64); vd += __shfl_xor(vd, 1, 64);
                vs += __shfl_xor(vs, 2, 64); vd += __shfl_xor(vd, 2, 64);
                vs += __shfl_xor(vs, 4, 64); vd += __shfl_xor(vd, 4, 64);
                if ((lane & 7) == 0) {
                    a_src[node * 8 + (lane >> 3)] = vs;
                    a_dst[node * 8 + (lane >> 3)] = vd;
                }
            }
        }
    }
}

// ---------------- CSR build ----------------
__global__ __launch_bounds__(256) void gat_hist(
    const int* __restrict__ e_dst, int* __restrict__ deg, int E)
{
    int i = blockIdx.x * 256 + threadIdx.x;
    int b = i * 4;
    if (b + 3 < E) {
        int4 d = *reinterpret_cast<const int4*>(e_dst + b);
        atomicAdd(&deg[d.x], 1);
        atomicAdd(&deg[d.y], 1);
        atomicAdd(&deg[d.z], 1);
        atomicAdd(&deg[d.w], 1);
    } else {
        for (int k = b; k < E; ++k) atomicAdd(&deg[e_dst[k]], 1);
    }
}

// Per-chunk (1024 elems) exclusive scan; chunkSum[b] = chunk total.
__global__ __launch_bounds__(256) void gat_scan_chunks(
    const int* __restrict__ deg, int* __restrict__ off,
    int* __restrict__ chunkSum, int N)
{
    __shared__ int lds[256];
    const int t = threadIdx.x;
    const int base = blockIdx.x * 1024 + t * 4;
    int v0 = 0, v1 = 0, v2 = 0, v3 = 0;
    if (base + 0 < N) v0 = deg[base + 0];
    if (base + 1 < N) v1 = deg[base + 1];
    if (base + 2 < N) v2 = deg[base + 2];
    if (base + 3 < N) v3 = deg[base + 3];
    int s = v0 + v1 + v2 + v3;
    lds[t] = s;
    __syncthreads();
    #pragma unroll
    for (int d = 1; d < 256; d <<= 1) {
        int add = (t >= d) ? lds[t - d] : 0;
        __syncthreads();
        lds[t] += add;
        __syncthreads();
    }
    if (t == 255) chunkSum[blockIdx.x] = lds[255];
    int p = lds[t] - s;  // exclusive within chunk
    if (base + 0 < N) off[base + 0] = p; p += v0;
    if (base + 1 < N) off[base + 1] = p; p += v1;
    if (base + 2 < N) off[base + 2] = p; p += v2;
    if (base + 3 < N) off[base + 3] = p;
}

// Exclusive scan of chunk sums (nChunks <= 128) in one 128-thread block.
__global__ __launch_bounds__(128) void gat_scan_tops(
    const int* __restrict__ chunkSum, int* __restrict__ chunkBase,
    int* __restrict__ off, int nChunks, int N)
{
    __shared__ int lds[128];
    const int t = threadIdx.x;
    if (nChunks > 128) {               // safety fallback (not hit at N=100k)
        if (t == 0) {
            int run = 0;
            for (int i = 0; i < nChunks; ++i) { chunkBase[i] = run; run += chunkSum[i]; }
            off[N] = run;
        }
        return;
    }
    int v = (t < nChunks) ? chunkSum[t] : 0;
    lds[t] = v;
    __syncthreads();
    #pragma unroll
    for (int d = 1; d < 128; d <<= 1) {
        int add = (t >= d) ? lds[t - d] : 0;
        __syncthreads();
        lds[t] += add;
        __syncthreads();
    }
    if (t < nChunks) chunkBase[t] = lds[t] - v;
    if (t == nChunks - 1) off[N] = lds[t];
}

__global__ __launch_bounds__(256) void gat_add_base(
    int* __restrict__ off, int* __restrict__ cursor,
    const int* __restrict__ chunkBase, int N)
{
    int i = blockIdx.x * 256 + threadIdx.x;
    if (i < N) {
        int v = off[i] + chunkBase[i >> 10];
        off[i] = v;
        cursor[i] = v;
    }
}

// dst-range-partitioned fill (see round 5 notes).
__global__ __launch_bounds__(256) void gat_fill(
    const int* __restrict__ e_src, const int* __restrict__ e_dst,
    int* __restrict__ cursor, int* __restrict__ esrc, int E, int N)
{
    const int range = blockIdx.x & 7;
    const int chunk = blockIdx.x >> 3;
    const int lo = (int)(((long long)N * range) >> 3);
    const int hi = (int)(((long long)N * (range + 1)) >> 3);

    const int b = chunk * 1024 + threadIdx.x * 4;
    if (b + 3 < E) {
        int4 sv = *reinterpret_cast<const int4*>(e_src + b);
        int4 dv = *reinterpret_cast<const int4*>(e_dst + b);
        if (dv.x >= lo && dv.x < hi) esrc[atomicAdd(&cursor[dv.x], 1)] = sv.x;
        if (dv.y >= lo && dv.y < hi) esrc[atomicAdd(&cursor[dv.y], 1)] = sv.y;
        if (dv.z >= lo && dv.z < hi) esrc[atomicAdd(&cursor[dv.z], 1)] = sv.z;
        if (dv.w >= lo && dv.w < hi) esrc[atomicAdd(&cursor[dv.w], 1)] = sv.w;
    } else {
        for (int k = b; k < E; ++k) {
            int d = e_dst[k];
            if (d >= lo && d < hi) esrc[atomicAdd(&cursor[d], 1)] = e_src[k];
        }
    }
}

// ---------------- Kernel 2: gather + softmax + ELU ----------------
// One wave per dst node; lane = head*8 + sub. Per 8-edge batch, lane computes
// the softmax weight for (edge k+sub, head) ONCE (64 lanes = 8 edges x 8
// heads exactly), then redistributes via shfl (ds_bpermute, LDS pipe).
__global__ __launch_bounds__(256) void gat_gather(
    const int* __restrict__ off, const int* __restrict__ esrc,
    const float* __restrict__ h, const float* __restrict__ a_src,
    const float* __restrict__ a_dst, const float* __restrict__ bias,
    float* __restrict__ out, int N)
{
    const int node = blockIdx.x * 4 + (threadIdx.x >> 6);
    if (node >= N) return;
    const int lane = threadIdx.x & 63;
    const int head = lane >> 3;
    const int sub  = lane & 7;
    const int gbase = lane & 56;      // first lane of my head group

    const float ad = a_dst[node * 8 + head];
    // self-loop
    float e0 = a_src[node * 8 + head] + ad;
    e0 = e0 > 0.f ? e0 : 0.2f * e0;
    float w0 = __expf(e0);
    float acc = w0 * h[(uint32_t)node * 64u + (uint32_t)lane];
    float s = w0;

    const int beg = off[node], end = off[node + 1];
    for (int k = beg; k < end; k += 8) {
        // my (edge, head) weight
        const int ke = k + sub;
        const int kc = ke < end ? ke : end - 1;
        const int sm = esrc[kc];
        float a = a_src[(uint32_t)sm * 8u + (uint32_t)head] + ad;
        a = a > 0.f ? a : 0.2f * a;
        const float wm = (ke < end) ? __expf(a) : 0.f;

        // h-row offsets for all 8 edges (broadcast loads, 32-bit offsets)
        uint32_t hoff[8];
        #pragma unroll
        for (int u = 0; u < 8; ++u) {
            const int kk = k + u;
            const int sb = esrc[kk < end ? kk : end - 1];
            hoff[u] = (uint32_t)sb * 64u + (uint32_t)lane;
        }
        float hb[8];
        #pragma unroll
        for (int u = 0; u < 8; ++u) hb[u] = h[hoff[u]];

        #pragma unroll
        for (int u = 0; u < 8; ++u) {
            const float w = __shfl(wm, gbase | u, 64);
            acc += w * hb[u];
            s += w;
        }
    }

    float v = acc / (s + 1e-16f) + bias[lane];
    out[(uint32_t)node * 64u + (uint32_t)lane] = v > 0.f ? v : expm1f(v);
}

extern "C" void kernel_launch(void* const* d_in, const int* in_sizes, int n_in,
                              void* d_out, int out_size, void* d_ws, size_t ws_size,
                              hipStream_t stream)
{
    const float* x       = (const float*)d_in[0];
    const float* W       = (const float*)d_in[1];
    const float* att_src = (const float*)d_in[2];
    const float* att_dst = (const float*)d_in[3];
    const float* bias    = (const float*)d_in[4];
    const int*   ei      = (const int*)d_in[5];   // int32 (JAX x64 disabled)

    const int N = in_sizes[0] / 128;
    const int E = in_sizes[5] / 2;
    const int nChunks = (N + 1023) / 1024;

    float* out = (float*)d_out;

    // workspace layout (all 4-byte elems)
    float* h        = (float*)d_ws;                    // N*64
    float* a_src    = h + (size_t)N * 64;              // N*8
    float* a_dst    = a_src + (size_t)N * 8;           // N*8
    int*   deg      = (int*)(a_dst + (size_t)N * 8);   // N
    int*   off      = deg + N;                         // N+1
    int*   cursor   = off + N + 1;                     // N
    int*   chunkSum = cursor + N;                      // nChunks
    int*   chunkBase= chunkSum + nChunks;              // nChunks
    int*   esrc     = chunkBase + nChunks;             // E

    const int* e_src = ei;
    const int* e_dst = ei + E;

    hipMemsetAsync(deg, 0, (size_t)N * sizeof(int), stream);

    gat_linear<<<1024, 256, 0, stream>>>(x, W, att_src, att_dst, h, a_src, a_dst, N);

    int eb4 = (E / 4 + 256) / 256;
    gat_hist<<<eb4, 256, 0, stream>>>(e_dst, deg, E);
    gat_scan_chunks<<<nChunks, 256, 0, stream>>>(deg, off, chunkSum, N);
    gat_scan_tops<<<1, 128, 0, stream>>>(chunkSum, chunkBase, off, nChunks, N);
    gat_add_base<<<(N + 255) / 256, 256, 0, stream>>>(off, cursor, chunkBase, N);

    int nChunksE = (E + 1023) / 1024;
    gat_fill<<<nChunksE * 8, 256, 0, stream>>>(e_src, e_dst, cursor, esrc, E, N);

    gat_gather<<<(N + 3) / 4, 256, 0, stream>>>(off, esrc, h, a_src, a_dst, bias, out, N);
}